// Round 1
// baseline (2493.776 us; speedup 1.0000x reference)
//
#include <hip/hip_runtime.h>
#include <math.h>

#define N 16384
#define IN_DIM 5000
#define HID 64
#define NLEV 11
#define SPLITK 32
#define KCH (N / SPLITK)   /* 512 */
#define LDK 72             /* LDS k-stride in shorts: 144 B, keeps 16B alignment for b128 */

typedef __attribute__((ext_vector_type(8))) short bf16x8;
typedef __attribute__((ext_vector_type(4))) float f32x4;

// Split fp32 into bf16 hi + bf16 lo (truncation; combined ~2^-16 rel error).
__device__ __forceinline__ void split2(float f, short& hi, short& lo) {
    unsigned u = __float_as_uint(f);
    unsigned hu = u & 0xffff0000u;
    float lf = f - __uint_as_float(hu);          // exact
    hi = (short)(unsigned short)(hu >> 16);
    lo = (short)(unsigned short)(__float_as_uint(lf) >> 16);
}

// bf16x3 MFMA over a staged 64x64 tile (K=64). 4 waves: wave (wm,wn) owns
// rows [wm*32,wm*32+32) x cols [wn*32,wn*32+32). A is [row][k], B is [col][k].
__device__ __forceinline__ void mfma_tile(const short (*aH)[LDK], const short (*aL)[LDK],
                                          const short (*bH)[LDK], const short (*bL)[LDK],
                                          int wm, int wn, int lane, f32x4 acc[2][2]) {
    int lr = lane & 15;
    int kg = (lane >> 4) * 8;
    #pragma unroll
    for (int ks = 0; ks < 64; ks += 32) {
        bf16x8 ah[2], al[2], bh[2], bl[2];
        #pragma unroll
        for (int mi = 0; mi < 2; mi++) {
            ah[mi] = *(const bf16x8*)&aH[wm * 32 + mi * 16 + lr][ks + kg];
            al[mi] = *(const bf16x8*)&aL[wm * 32 + mi * 16 + lr][ks + kg];
        }
        #pragma unroll
        for (int nj = 0; nj < 2; nj++) {
            bh[nj] = *(const bf16x8*)&bH[wn * 32 + nj * 16 + lr][ks + kg];
            bl[nj] = *(const bf16x8*)&bL[wn * 32 + nj * 16 + lr][ks + kg];
        }
        #pragma unroll
        for (int mi = 0; mi < 2; mi++) {
            #pragma unroll
            for (int nj = 0; nj < 2; nj++) {
                acc[mi][nj] = __builtin_amdgcn_mfma_f32_16x16x32_bf16(ah[mi], bh[nj], acc[mi][nj], 0, 0, 0);
                acc[mi][nj] = __builtin_amdgcn_mfma_f32_16x16x32_bf16(ah[mi], bl[nj], acc[mi][nj], 0, 0, 0);
                acc[mi][nj] = __builtin_amdgcn_mfma_f32_16x16x32_bf16(al[mi], bh[nj], acc[mi][nj], 0, 0, 0);
            }
        }
    }
}

// ---------------- level compaction (unchanged, verified) ----------------
__global__ __launch_bounds__(256) void compact_kernel(const int* __restrict__ level,
                                                      int* __restrict__ rows_sorted,
                                                      int* __restrict__ offs) {
    __shared__ int cnt[NLEV + 1];
    __shared__ int off_s[NLEV + 1];
    int t = threadIdx.x;
    if (t <= NLEV) cnt[t] = 0;
    __syncthreads();
    for (int i = t; i < N; i += 256) atomicAdd(&cnt[level[i]], 1);
    __syncthreads();
    if (t == 0) {
        int run = 0;
        for (int l = 0; l < NLEV; ++l) { off_s[l] = run; run += cnt[l]; }
        off_s[NLEV] = run;
        for (int l = 0; l <= NLEV; ++l) offs[l] = off_s[l];
    }
    __syncthreads();
    if (t <= NLEV) cnt[t] = off_s[t];
    __syncthreads();
    for (int i = t; i < N; i += 256) {
        int p = atomicAdd(&cnt[level[i]], 1);
        rows_sorted[p] = i;
    }
}

// ---------------- embedding GEMM: xhat = tfidf @ E_w (bf16x3 MFMA) ----------------
// grid 256 rowblocks, block 256. Direct stores (no split-K, no zeroing).
__global__ __launch_bounds__(256) void embed_kernel(const float* __restrict__ tfidf,
                                                    const float* __restrict__ Ew,
                                                    float* __restrict__ xhat) {
    __shared__ short aH[64][LDK], aL[64][LDK];
    __shared__ short bH[64][LDK], bL[64][LDK];
    int row0 = blockIdx.x * 64;
    int t = threadIdx.x;
    int lane = t & 63, wave = t >> 6;
    int wm = wave >> 1, wn = wave & 1;
    int srow = t >> 4, sk4 = (t & 15) * 4;   // A staging: row srow+16i, k sk4..sk4+3
    int sc = t >> 2, sk2 = (t & 3) * 2;      // B staging: col sc, k-pairs sk2+8i
    f32x4 acc[2][2] = {};
    for (int kt = 0; kt < IN_DIM; kt += 64) {
        int kw = IN_DIM - kt; if (kw > 64) kw = 64;
        // stage A (tfidf rows), zero-padded tail
        #pragma unroll
        for (int i = 0; i < 4; i++) {
            int r = i * 16 + srow;
            const float* src = tfidf + (size_t)(row0 + r) * IN_DIM + kt + sk4;
            float4 v;
            if (sk4 + 3 < kw) {
                v = *(const float4*)src;
            } else {
                float tmp[4] = {0.f, 0.f, 0.f, 0.f};
                for (int q = 0; q < 4; q++) if (sk4 + q < kw) tmp[q] = src[q];
                v = make_float4(tmp[0], tmp[1], tmp[2], tmp[3]);
            }
            short4 hv, lv;
            split2(v.x, hv.x, lv.x); split2(v.y, hv.y, lv.y);
            split2(v.z, hv.z, lv.z); split2(v.w, hv.w, lv.w);
            *(short4*)&aH[r][sk4] = hv;
            *(short4*)&aL[r][sk4] = lv;
        }
        // stage B transposed: bH[c][k] = bf16(Ew[kt+k][c]), zero-padded tail
        #pragma unroll
        for (int i = 0; i < 8; i++) {
            int k = sk2 + i * 8;
            float f0 = (k     < kw) ? Ew[(size_t)(kt + k) * HID + sc]     : 0.f;
            float f1 = (k + 1 < kw) ? Ew[(size_t)(kt + k + 1) * HID + sc] : 0.f;
            short h0, l0, h1, l1;
            split2(f0, h0, l0); split2(f1, h1, l1);
            *(short2*)&bH[sc][k] = make_short2(h0, h1);
            *(short2*)&bL[sc][k] = make_short2(l0, l1);
        }
        __syncthreads();
        mfma_tile(aH, aL, bH, bL, wm, wn, lane, acc);
        __syncthreads();
    }
    // C/D layout: col = lane&15, row = (lane>>4)*4 + reg
    #pragma unroll
    for (int mi = 0; mi < 2; mi++) {
        #pragma unroll
        for (int nj = 0; nj < 2; nj++) {
            int col = wn * 32 + nj * 16 + (lane & 15);
            #pragma unroll
            for (int v = 0; v < 4; v++) {
                int r = row0 + wm * 32 + mi * 16 + (lane >> 4) * 4 + v;
                xhat[(size_t)r * HID + col] = acc[mi][nj][v];
            }
        }
    }
}

// ---------------- xr/xz/xh = xhat @ {Wr,Wz,Wh} (unchanged, verified) ----------------
__global__ __launch_bounds__(256) void xproj_kernel(const float* __restrict__ xhat,
                                                    const float* __restrict__ Wr,
                                                    const float* __restrict__ Wz,
                                                    const float* __restrict__ Wh,
                                                    float* __restrict__ xr,
                                                    float* __restrict__ xz,
                                                    float* __restrict__ xh) {
    __shared__ float x_lds[64][68];
    __shared__ float w_lds[64][68];
    int t = threadIdx.x;
    int rg = t >> 4, c4 = (t & 15) * 4;
    int row0 = blockIdx.x * 64;
    #pragma unroll
    for (int i = 0; i < 4; i++) {
        int rl = i * 16 + rg;
        *(float4*)&x_lds[rl][c4] = *(const float4*)(xhat + (size_t)(row0 + rl) * HID + c4);
    }
    const float* Ws[3] = {Wr, Wz, Wh};
    float* outs[3] = {xr, xz, xh};
    for (int w = 0; w < 3; w++) {
        __syncthreads();
        #pragma unroll
        for (int i = 0; i < 4; i++) {
            int rl = i * 16 + rg;
            *(float4*)&w_lds[rl][c4] = *(const float4*)(Ws[w] + rl * HID + c4);
        }
        __syncthreads();
        float acc[4][4] = {};
        #pragma unroll 8
        for (int k = 0; k < 64; k++) {
            float4 bv = *(const float4*)&w_lds[k][c4];
            #pragma unroll
            for (int i = 0; i < 4; i++) {
                float av = x_lds[4 * rg + i][k];
                acc[i][0] += av * bv.x; acc[i][1] += av * bv.y;
                acc[i][2] += av * bv.z; acc[i][3] += av * bv.w;
            }
        }
        #pragma unroll
        for (int i = 0; i < 4; i++) {
            int r = row0 + 4 * rg + i;
            *(float4*)(outs[w] + (size_t)r * HID + c4) =
                make_float4(acc[i][0], acc[i][1], acc[i][2], acc[i][3]);
        }
    }
}

// ---------------- per-level masked GEMM: hs[rows] += adj[rows,:] @ h (bf16x3 MFMA) ----------------
__global__ __launch_bounds__(256) void hs_gemm(const float* __restrict__ adj,
                                               const float* __restrict__ h,
                                               float* __restrict__ hs,
                                               const int* __restrict__ rows_sorted,
                                               const int* __restrict__ offs, int lev) {
    __shared__ short aH[64][LDK], aL[64][LDK];
    __shared__ short bH[64][LDK], bL[64][LDK];
    __shared__ int ridx[64];
    int seg0 = offs[lev], seg1 = offs[lev + 1];
    int row0 = seg0 + blockIdx.x * 64;
    if (row0 >= seg1) return;
    int nval = seg1 - row0; if (nval > 64) nval = 64;
    int t = threadIdx.x;
    if (t < 64) {
        int p = row0 + t; if (p > seg1 - 1) p = seg1 - 1;
        ridx[t] = rows_sorted[p];
    }
    __syncthreads();
    int k0 = blockIdx.y * KCH;
    int lane = t & 63, wave = t >> 6;
    int wm = wave >> 1, wn = wave & 1;
    int srow = t >> 4, sk4 = (t & 15) * 4;
    int sc = t >> 2, sk2 = (t & 3) * 2;
    f32x4 acc[2][2] = {};
    for (int kt = 0; kt < KCH; kt += 64) {
        // stage A: adj[ridx[r]][k0+kt+k] -> bf16 hi/lo
        #pragma unroll
        for (int i = 0; i < 4; i++) {
            int r = i * 16 + srow;
            float4 v = *(const float4*)(adj + (size_t)ridx[r] * N + k0 + kt + sk4);
            short4 hv, lv;
            split2(v.x, hv.x, lv.x); split2(v.y, hv.y, lv.y);
            split2(v.z, hv.z, lv.z); split2(v.w, hv.w, lv.w);
            *(short4*)&aH[r][sk4] = hv;
            *(short4*)&aL[r][sk4] = lv;
        }
        // stage B transposed: bH[c][k] = bf16(h[k0+kt+k][c])
        const float* hb = h + (size_t)(k0 + kt) * HID + sc;
        #pragma unroll
        for (int i = 0; i < 8; i++) {
            int k = sk2 + i * 8;
            float f0 = hb[(size_t)k * HID];
            float f1 = hb[(size_t)(k + 1) * HID];
            short h0, l0, h1, l1;
            split2(f0, h0, l0); split2(f1, h1, l1);
            *(short2*)&bH[sc][k] = make_short2(h0, h1);
            *(short2*)&bL[sc][k] = make_short2(l0, l1);
        }
        __syncthreads();
        mfma_tile(aH, aL, bH, bL, wm, wn, lane, acc);
        __syncthreads();
    }
    #pragma unroll
    for (int mi = 0; mi < 2; mi++) {
        #pragma unroll
        for (int nj = 0; nj < 2; nj++) {
            int col = wn * 32 + nj * 16 + (lane & 15);
            #pragma unroll
            for (int v = 0; v < 4; v++) {
                int lrow = wm * 32 + mi * 16 + (lane >> 4) * 4 + v;
                if (lrow < nval)
                    atomicAdd(&hs[(size_t)ridx[lrow] * HID + col], acc[mi][nj][v]);
            }
        }
    }
}

// ---------------- per-level GRU gate update (unchanged, verified) ----------------
__global__ __launch_bounds__(256) void gate_kernel(const float* __restrict__ hs,
                                                   const float* __restrict__ xr,
                                                   const float* __restrict__ xz,
                                                   const float* __restrict__ xh,
                                                   const float* __restrict__ Ur,
                                                   const float* __restrict__ Uz,
                                                   const float* __restrict__ Uh,
                                                   float* __restrict__ h,
                                                   const int* __restrict__ rows_sorted,
                                                   const int* __restrict__ offs, int lev) {
    __shared__ float Ua[64][68];
    __shared__ float Ub[64][68];
    __shared__ float hs_lds[16][68];
    __shared__ float rh_lds[16][68];
    __shared__ int ridx[16];
    int seg0 = offs[lev], seg1 = offs[lev + 1];
    int row0 = seg0 + blockIdx.x * 16;
    if (row0 >= seg1) return;
    int nval = seg1 - row0; if (nval > 16) nval = 16;
    int t = threadIdx.x;
    if (t < 16) { int p = row0 + t; if (p > seg1 - 1) p = seg1 - 1; ridx[t] = rows_sorted[p]; }
    int rg = t >> 4, c4 = (t & 15) * 4;
    #pragma unroll
    for (int i = 0; i < 4; i++) {
        int rl = i * 16 + rg;
        *(float4*)&Ua[rl][c4] = *(const float4*)(Ur + rl * HID + c4);
        *(float4*)&Ub[rl][c4] = *(const float4*)(Uz + rl * HID + c4);
    }
    __syncthreads();
    {
        *(float4*)&hs_lds[rg][c4] = *(const float4*)(hs + (size_t)ridx[rg] * HID + c4);
    }
    __syncthreads();
    int row = rg;
    int grow = ridx[row];
    float ur[4] = {}, uz[4] = {};
    #pragma unroll 8
    for (int k = 0; k < 64; k++) {
        float hv = hs_lds[row][k];
        float4 rv = *(const float4*)&Ua[k][c4];
        float4 zv = *(const float4*)&Ub[k][c4];
        ur[0] += hv * rv.x; ur[1] += hv * rv.y; ur[2] += hv * rv.z; ur[3] += hv * rv.w;
        uz[0] += hv * zv.x; uz[1] += hv * zv.y; uz[2] += hv * zv.z; uz[3] += hv * zv.w;
    }
    float zz[4], hsv[4];
    #pragma unroll
    for (int m = 0; m < 4; m++) {
        hsv[m] = hs_lds[row][c4 + m];
        float xrv = xr[(size_t)grow * HID + c4 + m];
        float xzv = xz[(size_t)grow * HID + c4 + m];
        float rr = 1.f / (1.f + expf(-(xrv + ur[m])));
        zz[m] = 1.f / (1.f + expf(-(xzv + uz[m])));
        rh_lds[row][c4 + m] = hsv[m] * rr;
    }
    __syncthreads();
    #pragma unroll
    for (int i = 0; i < 4; i++) {
        int rl = i * 16 + rg;
        *(float4*)&Ua[rl][c4] = *(const float4*)(Uh + rl * HID + c4);
    }
    __syncthreads();
    float uh[4] = {};
    #pragma unroll 8
    for (int k = 0; k < 64; k++) {
        float rhv = rh_lds[row][k];
        float4 hv4 = *(const float4*)&Ua[k][c4];
        uh[0] += rhv * hv4.x; uh[1] += rhv * hv4.y; uh[2] += rhv * hv4.z; uh[3] += rhv * hv4.w;
    }
    if (row < nval) {
        #pragma unroll
        for (int m = 0; m < 4; m++) {
            float hh = tanhf(xh[(size_t)grow * HID + c4 + m] + uh[m]);
            float v = (1.f - zz[m]) * hsv[m] + zz[m] * hh;
            h[(size_t)grow * HID + c4 + m] = v;
        }
    }
}

// ---------------- root reduction + decoder (unchanged, verified) ----------------
__global__ __launch_bounds__(256) void final_kernel(const float* __restrict__ h,
                                                    const float* __restrict__ dec_w,
                                                    const float* __restrict__ dec_b,
                                                    const int* __restrict__ rows_sorted,
                                                    const int* __restrict__ offs,
                                                    float* __restrict__ out) {
    __shared__ float part[4][64];
    __shared__ float rep[64];
    int t = threadIdx.x;
    int c = t & 63, g = t >> 6;
    int s0 = offs[0], s1 = offs[1];
    float sum = 0.f;
    for (int p = s0 + g; p < s1; p += 4) {
        int r = rows_sorted[p];
        sum += h[(size_t)r * HID + c];
    }
    part[g][c] = sum;
    __syncthreads();
    if (t < 64) rep[t] = part[0][t] + part[1][t] + part[2][t] + part[3][t];
    __syncthreads();
    if (t < 4) {
        float acc = dec_b[t];
        for (int k = 0; k < HID; k++) acc += rep[k] * dec_w[k * 4 + t];
        out[t] = acc;
    }
}

extern "C" void kernel_launch(void* const* d_in, const int* in_sizes, int n_in,
                              void* d_out, int out_size, void* d_ws, size_t ws_size,
                              hipStream_t stream) {
    const float* adj   = (const float*)d_in[0];
    const float* tfidf = (const float*)d_in[1];
    const int*   level = (const int*)d_in[2];
    const float* Ew    = (const float*)d_in[3];
    const float* Wr    = (const float*)d_in[4];
    const float* Wz    = (const float*)d_in[5];
    const float* Ur    = (const float*)d_in[6];
    const float* Uz    = (const float*)d_in[7];
    const float* Wh    = (const float*)d_in[8];
    const float* Uh    = (const float*)d_in[9];
    const float* decw  = (const float*)d_in[10];
    const float* decb  = (const float*)d_in[11];
    float* ws = (float*)d_ws;
    const size_t SL = (size_t)N * HID;
    float* xr   = ws;
    float* xz   = ws + SL;
    float* xh   = ws + 2 * SL;
    float* h    = ws + 3 * SL;
    float* hs   = ws + 4 * SL;
    float* xhat = ws + 5 * SL;
    int* rows_sorted = (int*)(ws + 6 * SL);
    int* offs = rows_sorted + N;
    float* out = (float*)d_out;

    // zero h, hs (xhat is fully overwritten by embed's direct stores)
    hipMemsetAsync(h, 0, 2 * SL * sizeof(float), stream);
    compact_kernel<<<1, 256, 0, stream>>>(level, rows_sorted, offs);
    embed_kernel<<<256, 256, 0, stream>>>(tfidf, Ew, xhat);
    xproj_kernel<<<256, 256, 0, stream>>>(xhat, Wr, Wz, Wh, xr, xz, xh);
    for (int j = NLEV - 1; j >= 0; --j) {
        hs_gemm<<<dim3(256, SPLITK), 256, 0, stream>>>(adj, h, hs, rows_sorted, offs, j);
        gate_kernel<<<1024, 256, 0, stream>>>(hs, xr, xz, xh, Ur, Uz, Uh, h, rows_sorted, offs, j);
    }
    final_kernel<<<1, 256, 0, stream>>>(h, decw, decb, rows_sorted, offs, out);
}